// Round 13
// baseline (375.838 us; speedup 1.0000x reference)
//
#include <hip/hip_runtime.h>
#include <cstdint>
#include <cstddef>

#define BB 2
#define SS 2048
#define DD 1024
#define HH 16
#define DKK 64

typedef __attribute__((ext_vector_type(8))) short short8x;
typedef __attribute__((ext_vector_type(4))) float f32x4;

__device__ __forceinline__ unsigned short f2b(float f) {
  union { float f; unsigned u; } v; v.f = f;
  unsigned r = (v.u + 0x7fffu + ((v.u >> 16) & 1u)) >> 16;  // RNE
  return (unsigned short)r;
}

// hot-path bf16: round-half-up, 2 VALU (vs ~5 for RNE). Used only for Ps probabilities.
__device__ __forceinline__ unsigned short f2b_fast(float f) {
  union { float f; unsigned u; } v; v.f = f;
  return (unsigned short)((v.u + 0x8000u) >> 16);
}

__device__ __forceinline__ f32x4 mfma16(short8x a, short8x b, f32x4 c) {
  return __builtin_amdgcn_mfma_f32_16x16x32_bf16(a, b, c, 0, 0, 0);
}

// async global->LDS, 16B per lane. LDS dest = wave-uniform base + lane*16 (implicit).
__device__ __forceinline__ void gload16(const unsigned short* g, unsigned short* l) {
  __builtin_amdgcn_global_load_lds(
      (__attribute__((address_space(1))) unsigned int*)g,
      (__attribute__((address_space(3))) unsigned int*)l,
      16, 0, 0);
}

// Fragment-major Q/K layout (R5). R6: fixed m=0. R7: K-split + combine. R8: raw-HW
// transcendentals. R9 FAILED (flash spill at 8/EU). R10: XCD swizzle on flash.
// R11-R14: gemm_proj (256,5)+gload_lds+V-K1024. R12: K-compaction. R15: pack_w
// transpose + flash 128-row tiles. R16: flash kt-outer, gemm_out 64x128.
// R17: K-LDS staging, pack_x vectorized. R18: compacted-M K/V projection.
// R19: explicit block schedule for gemm_proj (107->85.5us, ~725 TF -- structure
// plateau; gemm_proj closed out).
// R20 (this round): probsmean K-staging DOUBLE BUFFER. R17's loop ran 2 barriers
// per h (32/block) and the stage->barrier->compute order drained vmcnt(0) before
// any compute: staging never overlapped. Ks[2] (32KB x 4 blocks = 128KB OK; flash
// can't: Ps+2*Ks > 160KB) -> 1-barrier pipeline: {barrier; issue stage(h+1) into
// other buf; compute h}. Barrier at h+1 both drains h's stage and protects buf
// (all waves past h's reads). Barriers halved, ~500cy load latency hidden under
// 48 MFMA + 64 trans chains.
#define C1F 0.0225421076f  // (1/64)*log2e
#define C2F 0.0541010849f  // (0.3/8)*log2e

// ---------------- pack weights: tiled transpose, coalesced both sides
__global__ __launch_bounds__(256) void pack_w_kernel(
    const float* __restrict__ Wq_r, const float* __restrict__ Wq_i,
    const float* __restrict__ Wk_r, const float* __restrict__ Wk_i,
    const float* __restrict__ Wv, const float* __restrict__ Wo,
    unsigned short* __restrict__ WcatT, unsigned short* __restrict__ WoT) {
  __shared__ float tile[64][65];
  const int tid = threadIdx.x;
  int bid = blockIdx.x;
  if (bid < 2560) {
    const int kt = bid & 31, nt = bid >> 5;
    const int k0 = kt * 64, n0 = nt * 64;
    const int q = n0 >> 10, j0 = n0 & 1023;
    const float* src;
    float sgn = 1.0f;
    bool zero = false;
    if (k0 < 1024) {
      src = (q == 0) ? Wq_r : (q == 1) ? Wq_i : (q == 2) ? Wk_r : (q == 3) ? Wk_i : Wv;
    } else {
      if (q == 0)      { src = Wq_i; sgn = -1.0f; }
      else if (q == 1) { src = Wq_r; }
      else if (q == 2) { src = Wk_i; sgn = -1.0f; }
      else if (q == 3) { src = Wk_r; }
      else             { src = Wv; zero = true; }
    }
    const int ks0 = k0 & 1023;
    if (!zero) {
#pragma unroll
      for (int i = 0; i < 16; i++) {
        int idx = i * 256 + tid;
        int r = idx >> 6, c = idx & 63;
        tile[r][c] = src[(size_t)(ks0 + r) * 1024 + j0 + c];
      }
      __syncthreads();
#pragma unroll
      for (int i = 0; i < 16; i++) {
        int idx = i * 256 + tid;
        int nr = idx >> 6, kc = idx & 63;
        WcatT[(size_t)(n0 + nr) * 2048 + k0 + kc] = f2b(sgn * tile[kc][nr]);
      }
    } else {
#pragma unroll
      for (int i = 0; i < 16; i++) {
        int idx = i * 256 + tid;
        int nr = idx >> 6, kc = idx & 63;
        WcatT[(size_t)(n0 + nr) * 2048 + k0 + kc] = 0;
      }
    }
  } else {
    bid -= 2560;
    const int kt = bid & 15, nt = bid >> 4;
    const int k0 = kt * 64, n0 = nt * 64;
#pragma unroll
    for (int i = 0; i < 16; i++) {
      int idx = i * 256 + tid;
      int r = idx >> 6, c = idx & 63;
      tile[r][c] = Wo[(size_t)(k0 + r) * 1024 + n0 + c];
    }
    __syncthreads();
#pragma unroll
    for (int i = 0; i < 16; i++) {
      int idx = i * 256 + tid;
      int nr = idx >> 6, kc = idx & 63;
      WoT[(size_t)(n0 + nr) * 1024 + k0 + kc] = f2b(tile[kc][nr]);
    }
  }
}

// ---------------- pack X (scatter unmasked rows into Xc2 segments)
__global__ void pack_x_kernel(const float* __restrict__ zr, const float* __restrict__ zi,
                              const unsigned short* __restrict__ pos,
                              unsigned short* __restrict__ X,
                              unsigned short* __restrict__ Xc2) {
  int gid = blockIdx.x * 256 + threadIdx.x;  // 1048576 threads x 8 elems
  int k8 = (gid & 255) << 3;                 // 0..2047 step 8 (never straddles 1024)
  int m = gid >> 8;
  const float* src = (k8 < 1024) ? (zr + (size_t)m * 1024 + k8)
                                 : (zi + (size_t)m * 1024 + (k8 - 1024));
  float4 a = *(const float4*)src;
  float4 c = *(const float4*)(src + 4);
  ushort4 o0; o0.x = f2b(a.x); o0.y = f2b(a.y); o0.z = f2b(a.z); o0.w = f2b(a.w);
  ushort4 o1; o1.x = f2b(c.x); o1.y = f2b(c.y); o1.z = f2b(c.z); o1.w = f2b(c.w);
  *(ushort4*)(X + (size_t)gid * 8) = o0;
  *(ushort4*)(X + (size_t)gid * 8 + 4) = o1;
  unsigned short pp = pos[m];
  if (pp != 0xFFFFu) {
    int b = m >> 11, s = m & 2047, half = s >> 10;
    size_t drow = (size_t)((b * 2 + half) * 1024 + pp);
    *(ushort4*)(Xc2 + drow * 2048 + k8) = o0;
    *(ushort4*)(Xc2 + drow * 2048 + k8 + 4) = o1;
  }
}

// ---------------- generic zero (float4 granularity)
__global__ void zero_kernel(float4* __restrict__ p) {
  p[(size_t)blockIdx.x * 256 + threadIdx.x] = float4{0.f, 0.f, 0.f, 0.f};
}

// ---------------- mask scan: per (b,half) compaction tables
__global__ void mask_scan_kernel(const int* __restrict__ mask,
                                 unsigned short* __restrict__ pos,
                                 unsigned short* __restrict__ idx,
                                 int* __restrict__ cnt) {
  const int b = blockIdx.x >> 1, half = blockIdx.x & 1;
  __shared__ int sums[256];
  const int t = threadIdx.x;
  const int s0 = half * 1024 + t * 4;
  int m[4];
  int loc = 0;
#pragma unroll
  for (int i = 0; i < 4; i++) { m[i] = mask[b * 2048 + s0 + i]; loc += m[i]; }
  sums[t] = loc;
  __syncthreads();
  for (int off = 1; off < 256; off <<= 1) {
    int v = (t >= off) ? sums[t - off] : 0;
    __syncthreads();
    sums[t] += v;
    __syncthreads();
  }
  int excl = sums[t] - loc;
#pragma unroll
  for (int i = 0; i < 4; i++) {
    int sg = s0 + i;
    if (m[i]) {
      pos[b * 2048 + sg] = (unsigned short)excl;
      idx[(b * 2 + half) * 1024 + excl] = (unsigned short)sg;
      excl++;
    } else {
      pos[b * 2048 + sg] = 0xFFFFu;
    }
  }
  if (t == 255) cnt[b * 2 + half] = sums[255];
}

// ---------------- build schedule: phase1 Q (512), phase2 K (16T), phase3 V (8T)
__global__ void build_sched_kernel(const int* __restrict__ cnt,
                                   ushort2* __restrict__ sched, int* __restrict__ nact) {
  __shared__ int off[5];
  const int t = threadIdx.x;
  if (t == 0) {
    int o = 0;
    for (int g = 0; g < 4; g++) { off[g] = o; o += (cnt[g] + 127) >> 7; }
    off[4] = o;
    *nact = 512 + 24 * o;
  }
  __syncthreads();
  const int T = off[4];
  const int total = 512 + 24 * T;
  for (int idx = t; idx < 1280; idx += 256) {
    ushort2 e;
    if (idx < 512) {
      e.x = (unsigned short)(idx & 31); e.y = (unsigned short)(idx >> 5);
    } else if (idx < 512 + 16 * T) {
      int k = idx - 512, mrank = k >> 4, ny = 16 + (k & 15);
      int g = 0;
      while (g < 3 && off[g + 1] <= mrank) g++;
      e.x = (unsigned short)(g * 8 + (mrank - off[g])); e.y = (unsigned short)ny;
    } else if (idx < total) {
      int k = idx - 512 - 16 * T, mrank = k >> 3, ny = 32 + (k & 7);
      int g = 0;
      while (g < 3 && off[g + 1] <= mrank) g++;
      e.x = (unsigned short)(g * 8 + (mrank - off[g])); e.y = (unsigned short)ny;
    } else {
      e.x = 0; e.y = 0;  // dead tail, never executed
    }
    sched[idx] = e;
  }
}

// ---------------- projection GEMM: 1D grid, schedule-table driven.
__global__ __launch_bounds__(256, 5) void gemm_proj_kernel(
    const unsigned short* __restrict__ A, const unsigned short* __restrict__ Ac,
    const unsigned short* __restrict__ Bt, const int* __restrict__ cnt,
    const ushort2* __restrict__ sched, const int* __restrict__ nact,
    unsigned short* __restrict__ Qr, unsigned short* __restrict__ Qi,
    unsigned short* __restrict__ Kr, unsigned short* __restrict__ Ki,
    unsigned short* __restrict__ VT) {
  constexpr int K = 2048;
  if ((int)blockIdx.x >= *nact) return;           // dead tail (dispatched last)
  const ushort2 e = sched[blockIdx.x];
  const int bx = e.x, by = e.y;
  const int n0 = by * 128;
  const bool qpath = (n0 < 2048);
  const int m0 = bx * 128;
  int cntg = 0;
  if (!qpath) cntg = cnt[bx >> 3];
  __shared__ __attribute__((aligned(16))) unsigned short As[128][32];
  __shared__ __attribute__((aligned(16))) unsigned short Bs[128][32];
  const int tid = threadIdx.x;
  const int lane = tid & 63, wid = tid >> 6;
  const int l15 = lane & 15, quad = lane >> 4;
  const int wm = (wid & 1) * 64, wn = (wid >> 1) * 64;
  const int r4 = lane >> 2, c8 = (lane & 3) * 8;
  // V columns (n >= 4096) have zero weights for k >= 1024: skip exactly.
  const int kmax = (n0 >= 4096) ? 1024 : K;
  f32x4 acc[4][4] = {};
  const unsigned short* Ab = qpath ? A : Ac;
  const unsigned short* pa0 = Ab + (size_t)(m0 + wid * 16 + r4) * K + c8;
  const unsigned short* pa1 = pa0 + (size_t)64 * K;
  const unsigned short* pb0 = Bt + (size_t)(n0 + wid * 16 + r4) * K + c8;
  const unsigned short* pb1 = pb0 + (size_t)64 * K;
  unsigned short* la0 = &As[wid * 16][0];
  unsigned short* la1 = &As[64 + wid * 16][0];
  unsigned short* lb0 = &Bs[wid * 16][0];
  unsigned short* lb1 = &Bs[64 + wid * 16][0];
  for (int k0 = 0; k0 < kmax; k0 += 32) {
    __syncthreads();
    gload16(pa0, la0);  gload16(pa1, la1);
    gload16(pb0, lb0);  gload16(pb1, lb1);
    pa0 += 32; pa1 += 32; pb0 += 32; pb1 += 32;
    __syncthreads();
    short8x af[4], bfr[4];
#pragma unroll
    for (int i = 0; i < 4; i++) af[i]  = *(const short8x*)&As[wm + i * 16 + l15][quad * 8];
#pragma unroll
    for (int i = 0; i < 4; i++) bfr[i] = *(const short8x*)&Bs[wn + i * 16 + l15][quad * 8];
#pragma unroll
    for (int mi = 0; mi < 4; mi++)
#pragma unroll
      for (int ni = 0; ni < 4; ni++)
        acc[mi][ni] = mfma16(af[mi], bfr[ni], acc[mi][ni]);
  }
  if (qpath) {
#pragma unroll
    for (int mi = 0; mi < 4; mi++)
#pragma unroll
      for (int ni = 0; ni < 4; ni++) {
        int gn = n0 + wn + ni * 16 + l15;
        int which = gn >> 10, j = gn & 1023, h = j >> 6, dk = j & 63;
        int ks = dk >> 5, q = (dk >> 3) & 3, e2 = dk & 7;
        unsigned short* dst = which ? Qi : Qr;
#pragma unroll
        for (int r = 0; r < 4; r++) {
          int gm = m0 + wm + mi * 16 + quad * 4 + r;
          int b = gm >> 11, s = gm & 2047;
          int bh = b * HH + h, rb = s >> 4, l = s & 15;
          dst[(size_t)(((bh * 128 + rb) * 2 + ks) * 512 + (q * 16 + l) * 8 + e2)] = f2b(acc[mi][ni][r]);
        }
      }
  } else {
    const int g = bx >> 3;
    const int b = g >> 1, hf = g & 1;
#pragma unroll
    for (int mi = 0; mi < 4; mi++)
#pragma unroll
      for (int ni = 0; ni < 4; ni++) {
        int gn = n0 + wn + ni * 16 + l15;
        if (gn < 4096) {
          // K: slot = local row
          int which = gn >> 10, j = gn & 1023, h = j >> 6, dk = j & 63;
          int ks = dk >> 5, q = (dk >> 3) & 3, e2 = dk & 7;
          unsigned short* dst = (which == 2) ? Kr : Ki;
#pragma unroll
          for (int r = 0; r < 4; r++) {
            int gm = m0 + wm + mi * 16 + quad * 4 + r;
            int local = gm & 1023;
            if (local < cntg) {
              int bh = b * HH + h, rb = hf * 64 + (local >> 4), l = local & 15;
              dst[(size_t)(((bh * 128 + rb) * 2 + ks) * 512 + (q * 16 + l) * 8 + e2)] = f2b(acc[mi][ni][r]);
            }
          }
        } else {
          // V^T: slot = local row
          int j = gn - 4096, h = j >> 6, dk = j & 63;
          int rbv = dk >> 4, lv = dk & 15;
#pragma unroll
          for (int r = 0; r < 4; r++) {
            int gm = m0 + wm + mi * 16 + quad * 4 + r;
            int local = gm & 1023;
            if (local < cntg) {
              int bh = b * HH + h, kc = hf * 32 + (local >> 5), qv = (local >> 3) & 3, ev = local & 7;
              VT[(size_t)(((bh * 4 + rbv) * 64 + kc) * 512 + (qv * 16 + lv) * 8 + ev)] = f2b(acc[mi][ni][r]);
            }
          }
        }
      }
  }
}

// ---------------- flash attention over COMPACTED keys, kt-outer/subtile-inner,
// K staged in LDS (single-buffered: Ps+2*Ks would exceed 160KB at 4 blocks/CU).
__global__ __launch_bounds__(256, 4) void flash_kernel(
    const unsigned short* __restrict__ Qr, const unsigned short* __restrict__ Qi,
    const unsigned short* __restrict__ Kr, const unsigned short* __restrict__ Ki,
    const unsigned short* __restrict__ VT, const int* __restrict__ cnt,
    float* __restrict__ ctxP0, float* __restrict__ ctxP1,
    float* __restrict__ Lp0, float* __restrict__ Lp1) {
  __shared__ __attribute__((aligned(16))) unsigned short Ps[2][4][16][72];
  __shared__ __attribute__((aligned(16))) unsigned short Ks[2][4][2][512];
  const int tid = threadIdx.x;
  const int lane = tid & 63, wid = tid >> 6;
  const int l15 = lane & 15, quad = lane >> 4;
  // XCD swizzle (bijective, 1024 % 8 == 0): each XCD gets 8 heads of one z.
  int lin = blockIdx.x + 16 * (blockIdx.y + 16 * blockIdx.z);
  lin = ((lin & 7) << 7) | (lin >> 3);
  const int qt2 = (lin & 15) * 128;
  const int h = (lin >> 4) & 15;
  const int z = lin >> 8;
  const int b = z >> 1, half = z & 1;
  const int bh = b * HH + h;
  float* __restrict__ cp = half ? ctxP1 : ctxP0;
  float* __restrict__ lp = half ? Lp1 : Lp0;
  const int cntbh = cnt[b * 2 + half];
  const int kend = ((cntbh + 63) >> 6) << 6;
  const int kt0 = half * 1024;

  // Q fragments for both 64-row subtiles
  short8x fqr0[2], fqr1[2], fqi0[2], fqi1[2];
#pragma unroll
  for (int s2 = 0; s2 < 2; s2++) {
    const int rb = ((qt2 + s2 * 64) >> 4) + wid;
    const int qb = (bh * 128 + rb) * 1024 + lane * 8;
    fqr0[s2] = *(const short8x*)(Qr + qb);
    fqr1[s2] = *(const short8x*)(Qr + qb + 512);
    fqi0[s2] = *(const short8x*)(Qi + qb);
    fqi1[s2] = *(const short8x*)(Qi + qb + 512);
  }
  f32x4 ctxacc[2][4] = {};
  float lsum[2][4] = {{0.f, 0.f, 0.f, 0.f}, {0.f, 0.f, 0.f, 0.f}};

  const int sf0 = wid * 4;

  for (int ktl = 0; ktl < kend; ktl += 64) {
    const int kt = kt0 + ktl;
    const int rbb = bh * 128 + (kt >> 4);
    __syncthreads();   // protect prior-iteration Ks reads
#pragma unroll
    for (int fi = 0; fi < 4; fi++) {
      int f = sf0 + fi;
      int arr = f >> 3, rbl = (f >> 1) & 3, ks = f & 1;
      const unsigned short* src = (arr ? Ki : Kr) + ((size_t)(rbb + rbl) * 2 + ks) * 512 + lane * 8;
      gload16(src, &Ks[arr][rbl][ks][0]);
    }
    __syncthreads();   // staged data visible to all waves
#pragma unroll
    for (int nb = 0; nb < 4; nb++) {
      const int j = ktl + nb * 16 + l15;           // compacted-local index
      short8x bkr0 = *(const short8x*)&Ks[0][nb][0][lane * 8];
      short8x bkr1 = *(const short8x*)&Ks[0][nb][1][lane * 8];
      short8x bki0 = *(const short8x*)&Ks[1][nb][0][lane * 8];
      short8x bki1 = *(const short8x*)&Ks[1][nb][1][lane * 8];
#pragma unroll
      for (int s2 = 0; s2 < 2; s2++) {
        f32x4 sr = {0.f, 0.f, 0.f, 0.f};
        sr = mfma16(fqr0[s2], bkr0, sr);  sr = mfma16(fqr1[s2], bkr1, sr);
        sr = mfma16(fqi0[s2], bki0, sr);  sr = mfma16(fqi1[s2], bki1, sr);
        f32x4 sa = {0.f, 0.f, 0.f, 0.f};
        sa = mfma16(fqi0[s2], bkr0, sa);  sa = mfma16(fqi1[s2], bkr1, sa);
        f32x4 sb = {0.f, 0.f, 0.f, 0.f};
        sb = mfma16(fqr0[s2], bki0, sb);  sb = mfma16(fqr1[s2], bki1, sb);
#pragma unroll
        for (int r = 0; r < 4; r++) {
          float a = sr[r];
          float d = sa[r] - sb[r];
          float r2 = __builtin_fmaf(a, a, d * d);
          float inv = __builtin_amdgcn_rsqf(r2);
          float arg = inv * __builtin_fmaf(C1F, r2, C2F * a);
          float p = (j < cntbh) ? __builtin_amdgcn_exp2f(arg) : 0.0f;  // select, not mul
          lsum[s2][r] += p;
          Ps[s2][wid][quad * 4 + r][nb * 16 + l15] = f2b_fast(p);
        }
      }
    }
    // PV: V loaded once (global), feeds both subtiles. V pad rows pre-zeroed.
#pragma unroll
    for (int ks = 0; ks < 2; ks++)
#pragma unroll
      for (int db = 0; db < 4; db++) {
        int voff = ((bh * 4 + db) * 64 + (kt >> 5) + ks) * 512 + lane * 8;
        short8x bv = *(const short8x*)(VT + voff);
        short8x ap0 = *(const short8x*)&Ps[0][wid][l15][ks * 32 + quad * 8];
        short8x ap1 = *(const short8x*)&Ps[1][wid][l15][ks * 32 + quad * 8];
        ctxacc[0][db] = mfma16(ap0, bv, ctxacc[0][db]);
        ctxacc[1][db] = mfma16(ap1, bv, ctxacc[1][db]);
      }
  }
#pragma unroll
  for (int s2 = 0; s2 < 2; s2++) {
#pragma unroll
    for (int r = 0; r < 4; r++) {
#pragma unroll
      for (int off = 1; off < 16; off <<= 1) lsum[s2][r] += __shfl_xor(lsum[s2][r], off, 64);
    }
#pragma unroll
    for (int r = 0; r < 4; r++) {
      int s = qt2 + s2 * 64 + wid * 16 + quad * 4 + r;
#pragma unroll
      for (int db = 0; db < 4; db++)
        cp[((size_t)b * SS + s) * DD + h * DKK + db * 16 + l15] = ctxacc[s2][db][r];
      if (l15 == 0) lp[(size_t)bh * SS + s] = lsum[s2][r];
    }
  }
}

// ---------------- combine: ctx_bf16 = (P0+P1) / (L0+L1)
__global__ __launch_bounds__(256) void combine_kernel(
    const float* __restrict__ ctxP0, const float* __restrict__ ctxP1,
    const float* __restrict__ Lp0, const float* __restrict__ Lp1,
    unsigned short* __restrict__ ctx) {
  int idx = blockIdx.x * 256 + threadIdx.x;   // 1048576 threads
  int g = idx * 4;
  int c = g & 1023, s = (g >> 10) & 2047, b = g >> 21;
  int h = c >> 6;
  size_t loff = (size_t)(b * HH + h) * SS + s;
  float linv = 1.0f / (Lp0[loff] + Lp1[loff]);
  float4 p0 = *(const float4*)(ctxP0 + g);
  float4 p1 = *(const float4*)(ctxP1 + g);
  ushort4 o;
  o.x = f2b((p0.x + p1.x) * linv);
  o.y = f2b((p0.y + p1.y) * linv);
  o.z = f2b((p0.z + p1.z) * linv);
  o.w = f2b((p0.w + p1.w) * linv);
  *(ushort4*)(ctx + g) = o;
}

// ---------------- output GEMM: out = ctx @ WoT^T + bias (64x128 tiles, 512 blocks)
__global__ __launch_bounds__(256, 2) void gemm_out_kernel(
    const unsigned short* __restrict__ A, const unsigned short* __restrict__ Bt,
    const float* __restrict__ bias, float* __restrict__ out) {
  constexpr int K = 1024;
  __shared__ __attribute__((aligned(16))) unsigned short As[64][32];
  __shared__ __attribute__((aligned(16))) unsigned short Bs[128][32];
  const int tid = threadIdx.x;
  const int m0 = blockIdx.x * 64;
  const int n0 = blockIdx.y * 128;
  const int lane = tid & 63, wid = tid >> 6;
  const int l15 = lane & 15, quad = lane >> 4;
  const int wm = (wid & 1) * 32, wn = (wid >> 1) * 64;
  const int r4 = lane >> 2, c8 = (lane & 3) * 8;
  f32x4 acc[2][4] = {};
  const unsigned short* pa0 = A + (size_t)(m0 + wid * 16 + r4) * K + c8;
  const unsigned short* pb0 = Bt + (size_t)(n0 + wid * 16 + r4) * K + c8;
  const unsigned short* pb1 = pb0 + (size_t)64 * K;
  unsigned short* la0 = &As[wid * 16][0];
  unsigned short* lb0 = &Bs[wid * 16][0];
  unsigned short* lb1 = &Bs[64 + wid * 16][0];
  for (int k0 = 0; k0 < K; k0 += 32) {
    __syncthreads();
    gload16(pa0, la0);
    gload16(pb0, lb0);  gload16(pb1, lb1);
    pa0 += 32; pb0 += 32; pb1 += 32;
    __syncthreads();
    short8x af[2], bfr[4];
#pragma unroll
    for (int i = 0; i < 2; i++) af[i]  = *(const short8x*)&As[wm + i * 16 + l15][quad * 8];
#pragma unroll
    for (int i = 0; i < 4; i++) bfr[i] = *(const short8x*)&Bs[wn + i * 16 + l15][quad * 8];
#pragma unroll
    for (int mi = 0; mi < 2; mi++)
#pragma unroll
      for (int ni = 0; ni < 4; ni++)
        acc[mi][ni] = mfma16(af[mi], bfr[ni], acc[mi][ni]);
  }
#pragma unroll
  for (int mi = 0; mi < 2; mi++)
#pragma unroll
    for (int ni = 0; ni < 4; ni++) {
      int gn = n0 + wn + ni * 16 + l15;
      float bv = bias[gn];
#pragma unroll
      for (int r = 0; r < 4; r++) {
        int gm = m0 + wm + mi * 16 + quad * 4 + r;
        out[(size_t)gm * 1024 + gn] = acc[mi][ni][r] + bv;
      }
    }
}

// ---------------- probs_mean over COMPACTED keys, DOUBLE-BUFFERED K staging (R20):
// prologue stages h=0; loop h: {barrier; issue stage(h+1) into other buffer;
// compute h}. Barrier at h+1 drains h's stage AND protects buf[h&1] (all waves
// past h's reads before the h+2 stage overwrites it). 16 barriers vs 32; stage
// latency hides under compute. out2 pre-zeroed, valid columns scattered via idx.
__global__ __launch_bounds__(256, 4) void probsmean_kernel(
    const unsigned short* __restrict__ Qr, const unsigned short* __restrict__ Qi,
    const unsigned short* __restrict__ Kr, const unsigned short* __restrict__ Ki,
    const int* __restrict__ cnt, const unsigned short* __restrict__ idxT,
    const float* __restrict__ Lp0, const float* __restrict__ Lp1,
    float* __restrict__ out2) {
  __shared__ __attribute__((aligned(16))) unsigned short Ks[2][2][4][2][512];
  const int tid = threadIdx.x, lane = tid & 63, wid = tid >> 6;
  const int l15 = lane & 15, quad = lane >> 4;
  const int qt = blockIdx.x * 64;
  const int b = blockIdx.z;
  const int c0 = cnt[b * 2], c1 = cnt[b * 2 + 1];
  const int t0n = (c0 + 63) >> 6;
  const int t1n = (c1 + 63) >> 6;
  const int t = blockIdx.y;
  int half, jl0, cnth;
  if (t < t0n)            { half = 0; jl0 = t * 64;         cnth = c0; }
  else if (t < t0n + t1n) { half = 1; jl0 = (t - t0n) * 64; cnth = c1; }
  else return;  // out2 pre-zeroed (block-uniform exit, before any barrier)
  const int qrow0 = qt + wid * 16;
  const int qrb = (qt >> 4) + wid;
  const int ktb = half * 64 + (jl0 >> 4);
  const int sf0 = wid * 4;
  int korig[4]; bool vld[4];
#pragma unroll
  for (int nb = 0; nb < 4; nb++) {
    int j = jl0 + nb * 16 + l15;
    vld[nb] = j < cnth;
    korig[nb] = idxT[(b * 2 + half) * 1024 + j];
  }
  // staging identity: frags f = wid*4+fi -> arr=f>>3, rbl=(f>>1)&3, ks=f&1
  const int f0arr = (sf0) >> 3;
  float psum[4][4] = {};  // [nb][r]
  // prologue: stage h=0 into buffer 0
  {
    const int rbb = (b * HH + 0) * 128 + ktb;
#pragma unroll
    for (int fi = 0; fi < 4; fi++) {
      int f = sf0 + fi;
      int arr = f >> 3, rbl = (f >> 1) & 3, ks = f & 1;
      const unsigned short* src = (arr ? Ki : Kr) + ((size_t)(rbb + rbl) * 2 + ks) * 512 + lane * 8;
      gload16(src, &Ks[0][arr][rbl][ks][0]);
    }
  }
  for (int h = 0; h < HH; h++) {
    const int bh = b * HH + h;
    const int cur = h & 1;
    __syncthreads();   // drains stage(h) AND ends all waves' reads of buf[cur] from h-1's overwrite window
    if (h + 1 < HH) {
      const int rbb = (bh + 1) * 128 + ktb;
#pragma unroll
      for (int fi = 0; fi < 4; fi++) {
        int f = sf0 + fi;
        int arr = f >> 3, rbl = (f >> 1) & 3, ks = f & 1;
        const unsigned short* src = (arr ? Ki : Kr) + ((size_t)(rbb + rbl) * 2 + ks) * 512 + lane * 8;
        gload16(src, &Ks[cur ^ 1][arr][rbl][ks][0]);
      }
    }
    const int qoff = (bh * 128 + qrb) * 1024 + lane * 8;
    short8x fqr0 = *(const short8x*)(Qr + qoff);
    short8x fqr1 = *(const short8x*)(Qr + qoff + 512);
    short8x fqi0 = *(const short8x*)(Qi + qoff);
    short8x fqi1 = *(const short8x*)(Qi + qoff + 512);
    const float4 lv0 = *(const float4*)(Lp0 + (size_t)bh * SS + qrow0 + quad * 4);
    const float4 lv1 = *(const float4*)(Lp1 + (size_t)bh * SS + qrow0 + quad * 4);
    float li[4];
    li[0] = 1.0f / (lv0.x + lv1.x); li[1] = 1.0f / (lv0.y + lv1.y);
    li[2] = 1.0f / (lv0.z + lv1.z); li[3] = 1.0f / (lv0.w + lv1.w);
#pragma unroll
    for (int nb = 0; nb < 4; nb++) {
      short8x bkr0 = *(const short8x*)&Ks[cur][0][nb][0][lane * 8];
      short8x bkr1 = *(const short8x*)&Ks[cur][0][nb][1][lane * 8];
      short8x bki0 = *(const short8x*)&Ks[cur][1][nb][0][lane * 8];
      short8x bki1 = *(const short8x*)&Ks[cur][1][nb][1][lane * 8];
      f32x4 sr = {0.f, 0.f, 0.f, 0.f};
      sr = mfma16(fqr0, bkr0, sr);  sr = mfma16(fqr1, bkr1, sr);
      sr = mfma16(fqi0, bki0, sr);  sr = mfma16(fqi1, bki1, sr);
      f32x4 sa = {0.f, 0.f, 0.f, 0.f};  // Qi.Kr
      sa = mfma16(fqi0, bkr0, sa);  sa = mfma16(fqi1, bkr1, sa);
      f32x4 sb = {0.f, 0.f, 0.f, 0.f};  // Qr.Ki
      sb = mfma16(fqr0, bki0, sb);  sb = mfma16(fqr1, bki1, sb);
#pragma unroll
      for (int r = 0; r < 4; r++) {
        float a = sr[r];
        float d = sa[r] - sb[r];
        float r2 = __builtin_fmaf(a, a, d * d);
        float inv = __builtin_amdgcn_rsqf(r2);
        float arg = inv * __builtin_fmaf(C1F, r2, C2F * a);
        float p = vld[nb] ? __builtin_amdgcn_exp2f(arg) * li[r] : 0.0f;  // select
        psum[nb][r] += p;
      }
    }
  }
#pragma unroll
  for (int nb = 0; nb < 4; nb++)
#pragma unroll
    for (int r = 0; r < 4; r++) {
      if (vld[nb]) {
        int qrow = qrow0 + quad * 4 + r;
        out2[((size_t)b * SS + qrow) * SS + korig[nb]] = psum[nb][r] * 0.0625f;
      }
    }
}

extern "C" void kernel_launch(void* const* d_in, const int* in_sizes, int n_in,
                              void* d_out, int out_size, void* d_ws, size_t ws_size,
                              hipStream_t stream) {
  const float* z_real = (const float*)d_in[0];
  const float* z_imag = (const float*)d_in[1];
  const float* Wq_r = (const float*)d_in[2];
  const float* Wq_i = (const float*)d_in[3];
  const float* Wk_r = (const float*)d_in[4];
  const float* Wk_i = (const float*)d_in[5];
  const float* Wv   = (const float*)d_in[6];
  const float* Wo_w = (const float*)d_in[7];
  const float* Wo_b = (const float*)d_in[8];
  const int*   mask = (const int*)d_in[9];
  char* ws = (char*)d_ws;

  // ws layout (bytes). ctxP0/ctxP1 ALIAS WcatT/Xcat: dead after gemm_proj (stream-serial).
  constexpr size_t QKV_BYTES = 8388608;  // B*H*S*DK*2
  unsigned short* Qr   = (unsigned short*)(ws + 0);
  unsigned short* Qi   = (unsigned short*)(ws + QKV_BYTES);
  unsigned short* Kr   = (unsigned short*)(ws + 2 * QKV_BYTES);
  unsigned short* Ki   = (unsigned short*)(ws + 3 * QKV_BYTES);
  unsigned short* VT   = (unsigned short*)(ws + 4 * QKV_BYTES);
  unsigned short* ctx  = (unsigned short*)(ws + 5 * QKV_BYTES);              // 8 MB bf16
  unsigned short* WcatT= (unsigned short*)(ws + 50331648);                   // 20 MB
  unsigned short* WoT  = (unsigned short*)(ws + 71303168);                   // 2 MB
  unsigned short* Xcat = (unsigned short*)(ws + 73400320);                   // 16 MB
  float* ctxP0 = (float*)(ws + 50331648);                                    // aliases WcatT (16 MB)
  float* ctxP1 = (float*)(ws + 73400320);                                    // aliases Xcat (16 MB)
  float* Lp0   = (float*)(ws + 90177536);                                    // 256 KB
  float* Lp1   = (float*)(ws + 90439680);                                    // 256 KB

  float* out  = (float*)d_out;
  float* out2 = out + (size_t)BB * SS * DD;

  // Compaction tables + schedule in d_out scratch (dead until gemm_out;
  // probsmean reads idxT before combine/gemm_out).
  unsigned short* posT = (unsigned short*)out;       // [2][2048] = 8 KB
  unsigned short* idxT = posT + 4096;                // [2][2][1024] = 8 KB
  int* cntT = (int*)(idxT + 4096);                   // [2][2] = 16 B
  int* nactT = cntT + 4;                             // 4 B
  ushort2* schedT = (ushort2*)(cntT + 8);            // 1280 x 4 B = 5 KB
  // Xc2 (compacted X rows for K/V projection, 16 MB) aliases out2 scratch:
  // dead after gemm_proj; out2 zeroing moved to after gemm_proj.
  unsigned short* Xc2 = (unsigned short*)out2;

  mask_scan_kernel<<<dim3(4), dim3(256), 0, stream>>>(mask, posT, idxT, cntT);
  build_sched_kernel<<<dim3(1), dim3(256), 0, stream>>>(cntT, schedT, nactT);
  pack_w_kernel<<<dim3(2816), dim3(256), 0, stream>>>(Wq_r, Wq_i, Wk_r, Wk_i, Wv, Wo_w, WcatT, WoT);
  pack_x_kernel<<<dim3(4096), dim3(256), 0, stream>>>(z_real, z_imag, posT, Xcat, Xc2);
  zero_kernel<<<dim3(2048), dim3(256), 0, stream>>>((float4*)VT);            // 8 MB: V pad rows = 0
  gemm_proj_kernel<<<dim3(1280), dim3(256), 0, stream>>>(Xcat, Xc2, WcatT, cntT, schedT, nactT, Qr, Qi, Kr, Ki, VT);
  zero_kernel<<<dim3(8192), dim3(256), 0, stream>>>((float4*)out2);          // 32 MB: masked cols = 0
  flash_kernel<<<dim3(16, 16, 4), dim3(256), 0, stream>>>(Qr, Qi, Kr, Ki, VT, cntT, ctxP0, ctxP1, Lp0, Lp1);
  probsmean_kernel<<<dim3(32, 32, 2), dim3(256), 0, stream>>>(Qr, Qi, Kr, Ki, cntT, idxT, Lp0, Lp1, out2);
  combine_kernel<<<dim3(4096), dim3(256), 0, stream>>>(ctxP0, ctxP1, Lp0, Lp1, ctx);
  gemm_out_kernel<<<dim3(64, 8), dim3(256), 0, stream>>>(ctx, WoT, Wo_b, out);
}

// Round 14
// 363.025 us; speedup vs baseline: 1.0353x; 1.0353x over previous
//
#include <hip/hip_runtime.h>
#include <cstdint>
#include <cstddef>

#define BB 2
#define SS 2048
#define DD 1024
#define HH 16
#define DKK 64

typedef __attribute__((ext_vector_type(8))) short short8x;
typedef __attribute__((ext_vector_type(4))) float f32x4;

__device__ __forceinline__ unsigned short f2b(float f) {
  union { float f; unsigned u; } v; v.f = f;
  unsigned r = (v.u + 0x7fffu + ((v.u >> 16) & 1u)) >> 16;  // RNE
  return (unsigned short)r;
}

// hot-path bf16: round-half-up, 2 VALU (vs ~5 for RNE). Used only for Ps probabilities.
__device__ __forceinline__ unsigned short f2b_fast(float f) {
  union { float f; unsigned u; } v; v.f = f;
  return (unsigned short)((v.u + 0x8000u) >> 16);
}

__device__ __forceinline__ f32x4 mfma16(short8x a, short8x b, f32x4 c) {
  return __builtin_amdgcn_mfma_f32_16x16x32_bf16(a, b, c, 0, 0, 0);
}

// async global->LDS, 16B per lane. LDS dest = wave-uniform base + lane*16 (implicit).
__device__ __forceinline__ void gload16(const unsigned short* g, unsigned short* l) {
  __builtin_amdgcn_global_load_lds(
      (__attribute__((address_space(1))) unsigned int*)g,
      (__attribute__((address_space(3))) unsigned int*)l,
      16, 0, 0);
}

// Fragment-major Q/K layout (R5). R6: fixed m=0. R7: K-split + combine. R8: raw-HW
// transcendentals. R9 FAILED (flash spill at 8/EU). R10: XCD swizzle on flash.
// R11-R14: gemm_proj (256,5)+gload_lds+V-K1024. R12: K-compaction. R15: pack_w
// transpose + flash 128-row tiles. R16: flash kt-outer, gemm_out 64x128.
// R17: K-LDS staging, pack_x vectorized. R18: compacted-M K/V projection.
// R19: explicit block schedule for gemm_proj (85.5us, structure plateau).
// R20 REGRESSED (+5us): probsmean K double-buffer. probsmean is NOT barrier-bound
// (K loads are L2-hits covered by TLP); doubled LDS + deeper loop cost more than
// halved barriers saved. REVERTED to R19 single-buffer.
// R21 (this round): drop zero_VT. The active V-tile epilogue visits every pad slot
// inside covered tiles; guard now WRITES 0 instead of skipping -> all slots
// < ceil(cnt/128)*128 defined; flash reads only < ceil(cnt/64)*64 <= that bound.
// K pad slots stay garbage (consumers use selects). Saves the 8MB zero pass.
#define C1F 0.0225421076f  // (1/64)*log2e
#define C2F 0.0541010849f  // (0.3/8)*log2e

// ---------------- pack weights: tiled transpose, coalesced both sides
__global__ __launch_bounds__(256) void pack_w_kernel(
    const float* __restrict__ Wq_r, const float* __restrict__ Wq_i,
    const float* __restrict__ Wk_r, const float* __restrict__ Wk_i,
    const float* __restrict__ Wv, const float* __restrict__ Wo,
    unsigned short* __restrict__ WcatT, unsigned short* __restrict__ WoT) {
  __shared__ float tile[64][65];
  const int tid = threadIdx.x;
  int bid = blockIdx.x;
  if (bid < 2560) {
    const int kt = bid & 31, nt = bid >> 5;
    const int k0 = kt * 64, n0 = nt * 64;
    const int q = n0 >> 10, j0 = n0 & 1023;
    const float* src;
    float sgn = 1.0f;
    bool zero = false;
    if (k0 < 1024) {
      src = (q == 0) ? Wq_r : (q == 1) ? Wq_i : (q == 2) ? Wk_r : (q == 3) ? Wk_i : Wv;
    } else {
      if (q == 0)      { src = Wq_i; sgn = -1.0f; }
      else if (q == 1) { src = Wq_r; }
      else if (q == 2) { src = Wk_i; sgn = -1.0f; }
      else if (q == 3) { src = Wk_r; }
      else             { src = Wv; zero = true; }
    }
    const int ks0 = k0 & 1023;
    if (!zero) {
#pragma unroll
      for (int i = 0; i < 16; i++) {
        int idx = i * 256 + tid;
        int r = idx >> 6, c = idx & 63;
        tile[r][c] = src[(size_t)(ks0 + r) * 1024 + j0 + c];
      }
      __syncthreads();
#pragma unroll
      for (int i = 0; i < 16; i++) {
        int idx = i * 256 + tid;
        int nr = idx >> 6, kc = idx & 63;
        WcatT[(size_t)(n0 + nr) * 2048 + k0 + kc] = f2b(sgn * tile[kc][nr]);
      }
    } else {
#pragma unroll
      for (int i = 0; i < 16; i++) {
        int idx = i * 256 + tid;
        int nr = idx >> 6, kc = idx & 63;
        WcatT[(size_t)(n0 + nr) * 2048 + k0 + kc] = 0;
      }
    }
  } else {
    bid -= 2560;
    const int kt = bid & 15, nt = bid >> 4;
    const int k0 = kt * 64, n0 = nt * 64;
#pragma unroll
    for (int i = 0; i < 16; i++) {
      int idx = i * 256 + tid;
      int r = idx >> 6, c = idx & 63;
      tile[r][c] = Wo[(size_t)(k0 + r) * 1024 + n0 + c];
    }
    __syncthreads();
#pragma unroll
    for (int i = 0; i < 16; i++) {
      int idx = i * 256 + tid;
      int nr = idx >> 6, kc = idx & 63;
      WoT[(size_t)(n0 + nr) * 1024 + k0 + kc] = f2b(tile[kc][nr]);
    }
  }
}

// ---------------- pack X (scatter unmasked rows into Xc2 segments)
__global__ void pack_x_kernel(const float* __restrict__ zr, const float* __restrict__ zi,
                              const unsigned short* __restrict__ pos,
                              unsigned short* __restrict__ X,
                              unsigned short* __restrict__ Xc2) {
  int gid = blockIdx.x * 256 + threadIdx.x;  // 1048576 threads x 8 elems
  int k8 = (gid & 255) << 3;                 // 0..2047 step 8 (never straddles 1024)
  int m = gid >> 8;
  const float* src = (k8 < 1024) ? (zr + (size_t)m * 1024 + k8)
                                 : (zi + (size_t)m * 1024 + (k8 - 1024));
  float4 a = *(const float4*)src;
  float4 c = *(const float4*)(src + 4);
  ushort4 o0; o0.x = f2b(a.x); o0.y = f2b(a.y); o0.z = f2b(a.z); o0.w = f2b(a.w);
  ushort4 o1; o1.x = f2b(c.x); o1.y = f2b(c.y); o1.z = f2b(c.z); o1.w = f2b(c.w);
  *(ushort4*)(X + (size_t)gid * 8) = o0;
  *(ushort4*)(X + (size_t)gid * 8 + 4) = o1;
  unsigned short pp = pos[m];
  if (pp != 0xFFFFu) {
    int b = m >> 11, s = m & 2047, half = s >> 10;
    size_t drow = (size_t)((b * 2 + half) * 1024 + pp);
    *(ushort4*)(Xc2 + drow * 2048 + k8) = o0;
    *(ushort4*)(Xc2 + drow * 2048 + k8 + 4) = o1;
  }
}

// ---------------- generic zero (float4 granularity)
__global__ void zero_kernel(float4* __restrict__ p) {
  p[(size_t)blockIdx.x * 256 + threadIdx.x] = float4{0.f, 0.f, 0.f, 0.f};
}

// ---------------- mask scan: per (b,half) compaction tables
__global__ void mask_scan_kernel(const int* __restrict__ mask,
                                 unsigned short* __restrict__ pos,
                                 unsigned short* __restrict__ idx,
                                 int* __restrict__ cnt) {
  const int b = blockIdx.x >> 1, half = blockIdx.x & 1;
  __shared__ int sums[256];
  const int t = threadIdx.x;
  const int s0 = half * 1024 + t * 4;
  int m[4];
  int loc = 0;
#pragma unroll
  for (int i = 0; i < 4; i++) { m[i] = mask[b * 2048 + s0 + i]; loc += m[i]; }
  sums[t] = loc;
  __syncthreads();
  for (int off = 1; off < 256; off <<= 1) {
    int v = (t >= off) ? sums[t - off] : 0;
    __syncthreads();
    sums[t] += v;
    __syncthreads();
  }
  int excl = sums[t] - loc;
#pragma unroll
  for (int i = 0; i < 4; i++) {
    int sg = s0 + i;
    if (m[i]) {
      pos[b * 2048 + sg] = (unsigned short)excl;
      idx[(b * 2 + half) * 1024 + excl] = (unsigned short)sg;
      excl++;
    } else {
      pos[b * 2048 + sg] = 0xFFFFu;
    }
  }
  if (t == 255) cnt[b * 2 + half] = sums[255];
}

// ---------------- build schedule: phase1 Q (512), phase2 K (16T), phase3 V (8T)
__global__ void build_sched_kernel(const int* __restrict__ cnt,
                                   ushort2* __restrict__ sched, int* __restrict__ nact) {
  __shared__ int off[5];
  const int t = threadIdx.x;
  if (t == 0) {
    int o = 0;
    for (int g = 0; g < 4; g++) { off[g] = o; o += (cnt[g] + 127) >> 7; }
    off[4] = o;
    *nact = 512 + 24 * o;
  }
  __syncthreads();
  const int T = off[4];
  const int total = 512 + 24 * T;
  for (int idx = t; idx < 1280; idx += 256) {
    ushort2 e;
    if (idx < 512) {
      e.x = (unsigned short)(idx & 31); e.y = (unsigned short)(idx >> 5);
    } else if (idx < 512 + 16 * T) {
      int k = idx - 512, mrank = k >> 4, ny = 16 + (k & 15);
      int g = 0;
      while (g < 3 && off[g + 1] <= mrank) g++;
      e.x = (unsigned short)(g * 8 + (mrank - off[g])); e.y = (unsigned short)ny;
    } else if (idx < total) {
      int k = idx - 512 - 16 * T, mrank = k >> 3, ny = 32 + (k & 7);
      int g = 0;
      while (g < 3 && off[g + 1] <= mrank) g++;
      e.x = (unsigned short)(g * 8 + (mrank - off[g])); e.y = (unsigned short)ny;
    } else {
      e.x = 0; e.y = 0;  // dead tail, never executed
    }
    sched[idx] = e;
  }
}

// ---------------- projection GEMM: 1D grid, schedule-table driven.
// R21: V^T epilogue writes 0 for pad rows (local >= cntg) -> zero_VT pass dropped.
__global__ __launch_bounds__(256, 5) void gemm_proj_kernel(
    const unsigned short* __restrict__ A, const unsigned short* __restrict__ Ac,
    const unsigned short* __restrict__ Bt, const int* __restrict__ cnt,
    const ushort2* __restrict__ sched, const int* __restrict__ nact,
    unsigned short* __restrict__ Qr, unsigned short* __restrict__ Qi,
    unsigned short* __restrict__ Kr, unsigned short* __restrict__ Ki,
    unsigned short* __restrict__ VT) {
  constexpr int K = 2048;
  if ((int)blockIdx.x >= *nact) return;           // dead tail (dispatched last)
  const ushort2 e = sched[blockIdx.x];
  const int bx = e.x, by = e.y;
  const int n0 = by * 128;
  const bool qpath = (n0 < 2048);
  const int m0 = bx * 128;
  int cntg = 0;
  if (!qpath) cntg = cnt[bx >> 3];
  __shared__ __attribute__((aligned(16))) unsigned short As[128][32];
  __shared__ __attribute__((aligned(16))) unsigned short Bs[128][32];
  const int tid = threadIdx.x;
  const int lane = tid & 63, wid = tid >> 6;
  const int l15 = lane & 15, quad = lane >> 4;
  const int wm = (wid & 1) * 64, wn = (wid >> 1) * 64;
  const int r4 = lane >> 2, c8 = (lane & 3) * 8;
  // V columns (n >= 4096) have zero weights for k >= 1024: skip exactly.
  const int kmax = (n0 >= 4096) ? 1024 : K;
  f32x4 acc[4][4] = {};
  const unsigned short* Ab = qpath ? A : Ac;
  const unsigned short* pa0 = Ab + (size_t)(m0 + wid * 16 + r4) * K + c8;
  const unsigned short* pa1 = pa0 + (size_t)64 * K;
  const unsigned short* pb0 = Bt + (size_t)(n0 + wid * 16 + r4) * K + c8;
  const unsigned short* pb1 = pb0 + (size_t)64 * K;
  unsigned short* la0 = &As[wid * 16][0];
  unsigned short* la1 = &As[64 + wid * 16][0];
  unsigned short* lb0 = &Bs[wid * 16][0];
  unsigned short* lb1 = &Bs[64 + wid * 16][0];
  for (int k0 = 0; k0 < kmax; k0 += 32) {
    __syncthreads();
    gload16(pa0, la0);  gload16(pa1, la1);
    gload16(pb0, lb0);  gload16(pb1, lb1);
    pa0 += 32; pa1 += 32; pb0 += 32; pb1 += 32;
    __syncthreads();
    short8x af[4], bfr[4];
#pragma unroll
    for (int i = 0; i < 4; i++) af[i]  = *(const short8x*)&As[wm + i * 16 + l15][quad * 8];
#pragma unroll
    for (int i = 0; i < 4; i++) bfr[i] = *(const short8x*)&Bs[wn + i * 16 + l15][quad * 8];
#pragma unroll
    for (int mi = 0; mi < 4; mi++)
#pragma unroll
      for (int ni = 0; ni < 4; ni++)
        acc[mi][ni] = mfma16(af[mi], bfr[ni], acc[mi][ni]);
  }
  if (qpath) {
#pragma unroll
    for (int mi = 0; mi < 4; mi++)
#pragma unroll
      for (int ni = 0; ni < 4; ni++) {
        int gn = n0 + wn + ni * 16 + l15;
        int which = gn >> 10, j = gn & 1023, h = j >> 6, dk = j & 63;
        int ks = dk >> 5, q = (dk >> 3) & 3, e2 = dk & 7;
        unsigned short* dst = which ? Qi : Qr;
#pragma unroll
        for (int r = 0; r < 4; r++) {
          int gm = m0 + wm + mi * 16 + quad * 4 + r;
          int b = gm >> 11, s = gm & 2047;
          int bh = b * HH + h, rb = s >> 4, l = s & 15;
          dst[(size_t)(((bh * 128 + rb) * 2 + ks) * 512 + (q * 16 + l) * 8 + e2)] = f2b(acc[mi][ni][r]);
        }
      }
  } else {
    const int g = bx >> 3;
    const int b = g >> 1, hf = g & 1;
#pragma unroll
    for (int mi = 0; mi < 4; mi++)
#pragma unroll
      for (int ni = 0; ni < 4; ni++) {
        int gn = n0 + wn + ni * 16 + l15;
        if (gn < 4096) {
          // K: slot = local row (pad slots stay garbage; consumers select)
          int which = gn >> 10, j = gn & 1023, h = j >> 6, dk = j & 63;
          int ks = dk >> 5, q = (dk >> 3) & 3, e2 = dk & 7;
          unsigned short* dst = (which == 2) ? Kr : Ki;
#pragma unroll
          for (int r = 0; r < 4; r++) {
            int gm = m0 + wm + mi * 16 + quad * 4 + r;
            int local = gm & 1023;
            if (local < cntg) {
              int bh = b * HH + h, rb = hf * 64 + (local >> 4), l = local & 15;
              dst[(size_t)(((bh * 128 + rb) * 2 + ks) * 512 + (q * 16 + l) * 8 + e2)] = f2b(acc[mi][ni][r]);
            }
          }
        } else {
          // V^T: slot = local row; R21: pad rows write 0 (replaces zero_VT pass)
          int j = gn - 4096, h = j >> 6, dk = j & 63;
          int rbv = dk >> 4, lv = dk & 15;
#pragma unroll
          for (int r = 0; r < 4; r++) {
            int gm = m0 + wm + mi * 16 + quad * 4 + r;
            int local = gm & 1023;
            int bh = b * HH + h, kc = hf * 32 + (local >> 5), qv = (local >> 3) & 3, ev = local & 7;
            unsigned short v = (local < cntg) ? f2b(acc[mi][ni][r]) : (unsigned short)0;
            VT[(size_t)(((bh * 4 + rbv) * 64 + kc) * 512 + (qv * 16 + lv) * 8 + ev)] = v;
          }
        }
      }
  }
}

// ---------------- flash attention over COMPACTED keys, kt-outer/subtile-inner,
// K staged in LDS (single-buffered: Ps+2*Ks would exceed 160KB at 4 blocks/CU).
__global__ __launch_bounds__(256, 4) void flash_kernel(
    const unsigned short* __restrict__ Qr, const unsigned short* __restrict__ Qi,
    const unsigned short* __restrict__ Kr, const unsigned short* __restrict__ Ki,
    const unsigned short* __restrict__ VT, const int* __restrict__ cnt,
    float* __restrict__ ctxP0, float* __restrict__ ctxP1,
    float* __restrict__ Lp0, float* __restrict__ Lp1) {
  __shared__ __attribute__((aligned(16))) unsigned short Ps[2][4][16][72];
  __shared__ __attribute__((aligned(16))) unsigned short Ks[2][4][2][512];
  const int tid = threadIdx.x;
  const int lane = tid & 63, wid = tid >> 6;
  const int l15 = lane & 15, quad = lane >> 4;
  // XCD swizzle (bijective, 1024 % 8 == 0): each XCD gets 8 heads of one z.
  int lin = blockIdx.x + 16 * (blockIdx.y + 16 * blockIdx.z);
  lin = ((lin & 7) << 7) | (lin >> 3);
  const int qt2 = (lin & 15) * 128;
  const int h = (lin >> 4) & 15;
  const int z = lin >> 8;
  const int b = z >> 1, half = z & 1;
  const int bh = b * HH + h;
  float* __restrict__ cp = half ? ctxP1 : ctxP0;
  float* __restrict__ lp = half ? Lp1 : Lp0;
  const int cntbh = cnt[b * 2 + half];
  const int kend = ((cntbh + 63) >> 6) << 6;
  const int kt0 = half * 1024;

  // Q fragments for both 64-row subtiles
  short8x fqr0[2], fqr1[2], fqi0[2], fqi1[2];
#pragma unroll
  for (int s2 = 0; s2 < 2; s2++) {
    const int rb = ((qt2 + s2 * 64) >> 4) + wid;
    const int qb = (bh * 128 + rb) * 1024 + lane * 8;
    fqr0[s2] = *(const short8x*)(Qr + qb);
    fqr1[s2] = *(const short8x*)(Qr + qb + 512);
    fqi0[s2] = *(const short8x*)(Qi + qb);
    fqi1[s2] = *(const short8x*)(Qi + qb + 512);
  }
  f32x4 ctxacc[2][4] = {};
  float lsum[2][4] = {{0.f, 0.f, 0.f, 0.f}, {0.f, 0.f, 0.f, 0.f}};

  const int sf0 = wid * 4;

  for (int ktl = 0; ktl < kend; ktl += 64) {
    const int kt = kt0 + ktl;
    const int rbb = bh * 128 + (kt >> 4);
    __syncthreads();   // protect prior-iteration Ks reads
#pragma unroll
    for (int fi = 0; fi < 4; fi++) {
      int f = sf0 + fi;
      int arr = f >> 3, rbl = (f >> 1) & 3, ks = f & 1;
      const unsigned short* src = (arr ? Ki : Kr) + ((size_t)(rbb + rbl) * 2 + ks) * 512 + lane * 8;
      gload16(src, &Ks[arr][rbl][ks][0]);
    }
    __syncthreads();   // staged data visible to all waves
#pragma unroll
    for (int nb = 0; nb < 4; nb++) {
      const int j = ktl + nb * 16 + l15;           // compacted-local index
      short8x bkr0 = *(const short8x*)&Ks[0][nb][0][lane * 8];
      short8x bkr1 = *(const short8x*)&Ks[0][nb][1][lane * 8];
      short8x bki0 = *(const short8x*)&Ks[1][nb][0][lane * 8];
      short8x bki1 = *(const short8x*)&Ks[1][nb][1][lane * 8];
#pragma unroll
      for (int s2 = 0; s2 < 2; s2++) {
        f32x4 sr = {0.f, 0.f, 0.f, 0.f};
        sr = mfma16(fqr0[s2], bkr0, sr);  sr = mfma16(fqr1[s2], bkr1, sr);
        sr = mfma16(fqi0[s2], bki0, sr);  sr = mfma16(fqi1[s2], bki1, sr);
        f32x4 sa = {0.f, 0.f, 0.f, 0.f};
        sa = mfma16(fqi0[s2], bkr0, sa);  sa = mfma16(fqi1[s2], bkr1, sa);
        f32x4 sb = {0.f, 0.f, 0.f, 0.f};
        sb = mfma16(fqr0[s2], bki0, sb);  sb = mfma16(fqr1[s2], bki1, sb);
#pragma unroll
        for (int r = 0; r < 4; r++) {
          float a = sr[r];
          float d = sa[r] - sb[r];
          float r2 = __builtin_fmaf(a, a, d * d);
          float inv = __builtin_amdgcn_rsqf(r2);
          float arg = inv * __builtin_fmaf(C1F, r2, C2F * a);
          float p = (j < cntbh) ? __builtin_amdgcn_exp2f(arg) : 0.0f;  // select, not mul
          lsum[s2][r] += p;
          Ps[s2][wid][quad * 4 + r][nb * 16 + l15] = f2b_fast(p);
        }
      }
    }
    // PV: V loaded once (global), feeds both subtiles. V pad rows zeroed by gemm_proj.
#pragma unroll
    for (int ks = 0; ks < 2; ks++)
#pragma unroll
      for (int db = 0; db < 4; db++) {
        int voff = ((bh * 4 + db) * 64 + (kt >> 5) + ks) * 512 + lane * 8;
        short8x bv = *(const short8x*)(VT + voff);
        short8x ap0 = *(const short8x*)&Ps[0][wid][l15][ks * 32 + quad * 8];
        short8x ap1 = *(const short8x*)&Ps[1][wid][l15][ks * 32 + quad * 8];
        ctxacc[0][db] = mfma16(ap0, bv, ctxacc[0][db]);
        ctxacc[1][db] = mfma16(ap1, bv, ctxacc[1][db]);
      }
  }
#pragma unroll
  for (int s2 = 0; s2 < 2; s2++) {
#pragma unroll
    for (int r = 0; r < 4; r++) {
#pragma unroll
      for (int off = 1; off < 16; off <<= 1) lsum[s2][r] += __shfl_xor(lsum[s2][r], off, 64);
    }
#pragma unroll
    for (int r = 0; r < 4; r++) {
      int s = qt2 + s2 * 64 + wid * 16 + quad * 4 + r;
#pragma unroll
      for (int db = 0; db < 4; db++)
        cp[((size_t)b * SS + s) * DD + h * DKK + db * 16 + l15] = ctxacc[s2][db][r];
      if (l15 == 0) lp[(size_t)bh * SS + s] = lsum[s2][r];
    }
  }
}

// ---------------- combine: ctx_bf16 = (P0+P1) / (L0+L1)
__global__ __launch_bounds__(256) void combine_kernel(
    const float* __restrict__ ctxP0, const float* __restrict__ ctxP1,
    const float* __restrict__ Lp0, const float* __restrict__ Lp1,
    unsigned short* __restrict__ ctx) {
  int idx = blockIdx.x * 256 + threadIdx.x;   // 1048576 threads
  int g = idx * 4;
  int c = g & 1023, s = (g >> 10) & 2047, b = g >> 21;
  int h = c >> 6;
  size_t loff = (size_t)(b * HH + h) * SS + s;
  float linv = 1.0f / (Lp0[loff] + Lp1[loff]);
  float4 p0 = *(const float4*)(ctxP0 + g);
  float4 p1 = *(const float4*)(ctxP1 + g);
  ushort4 o;
  o.x = f2b((p0.x + p1.x) * linv);
  o.y = f2b((p0.y + p1.y) * linv);
  o.z = f2b((p0.z + p1.z) * linv);
  o.w = f2b((p0.w + p1.w) * linv);
  *(ushort4*)(ctx + g) = o;
}

// ---------------- output GEMM: out = ctx @ WoT^T + bias (64x128 tiles, 512 blocks)
__global__ __launch_bounds__(256, 2) void gemm_out_kernel(
    const unsigned short* __restrict__ A, const unsigned short* __restrict__ Bt,
    const float* __restrict__ bias, float* __restrict__ out) {
  constexpr int K = 1024;
  __shared__ __attribute__((aligned(16))) unsigned short As[64][32];
  __shared__ __attribute__((aligned(16))) unsigned short Bs[128][32];
  const int tid = threadIdx.x;
  const int m0 = blockIdx.x * 64;
  const int n0 = blockIdx.y * 128;
  const int lane = tid & 63, wid = tid >> 6;
  const int l15 = lane & 15, quad = lane >> 4;
  const int wm = (wid & 1) * 32, wn = (wid >> 1) * 64;
  const int r4 = lane >> 2, c8 = (lane & 3) * 8;
  f32x4 acc[2][4] = {};
  const unsigned short* pa0 = A + (size_t)(m0 + wid * 16 + r4) * K + c8;
  const unsigned short* pb0 = Bt + (size_t)(n0 + wid * 16 + r4) * K + c8;
  const unsigned short* pb1 = pb0 + (size_t)64 * K;
  unsigned short* la0 = &As[wid * 16][0];
  unsigned short* lb0 = &Bs[wid * 16][0];
  unsigned short* lb1 = &Bs[64 + wid * 16][0];
  for (int k0 = 0; k0 < K; k0 += 32) {
    __syncthreads();
    gload16(pa0, la0);
    gload16(pb0, lb0);  gload16(pb1, lb1);
    pa0 += 32; pb0 += 32; pb1 += 32;
    __syncthreads();
    short8x af[2], bfr[4];
#pragma unroll
    for (int i = 0; i < 2; i++) af[i]  = *(const short8x*)&As[wm + i * 16 + l15][quad * 8];
#pragma unroll
    for (int i = 0; i < 4; i++) bfr[i] = *(const short8x*)&Bs[wn + i * 16 + l15][quad * 8];
#pragma unroll
    for (int mi = 0; mi < 2; mi++)
#pragma unroll
      for (int ni = 0; ni < 4; ni++)
        acc[mi][ni] = mfma16(af[mi], bfr[ni], acc[mi][ni]);
  }
#pragma unroll
  for (int mi = 0; mi < 2; mi++)
#pragma unroll
    for (int ni = 0; ni < 4; ni++) {
      int gn = n0 + wn + ni * 16 + l15;
      float bv = bias[gn];
#pragma unroll
      for (int r = 0; r < 4; r++) {
        int gm = m0 + wm + mi * 16 + quad * 4 + r;
        out[(size_t)gm * 1024 + gn] = acc[mi][ni][r] + bv;
      }
    }
}

// ---------------- probs_mean over COMPACTED keys, K staged in LDS (R19 version;
// R20 double-buffer reverted). out2 pre-zeroed, valid columns scattered via idx.
__global__ __launch_bounds__(256, 4) void probsmean_kernel(
    const unsigned short* __restrict__ Qr, const unsigned short* __restrict__ Qi,
    const unsigned short* __restrict__ Kr, const unsigned short* __restrict__ Ki,
    const int* __restrict__ cnt, const unsigned short* __restrict__ idxT,
    const float* __restrict__ Lp0, const float* __restrict__ Lp1,
    float* __restrict__ out2) {
  __shared__ __attribute__((aligned(16))) unsigned short Ks[2][4][2][512];
  const int tid = threadIdx.x, lane = tid & 63, wid = tid >> 6;
  const int l15 = lane & 15, quad = lane >> 4;
  const int qt = blockIdx.x * 64;
  const int b = blockIdx.z;
  const int c0 = cnt[b * 2], c1 = cnt[b * 2 + 1];
  const int t0n = (c0 + 63) >> 6;
  const int t1n = (c1 + 63) >> 6;
  const int t = blockIdx.y;
  int half, jl0, cnth;
  if (t < t0n)            { half = 0; jl0 = t * 64;         cnth = c0; }
  else if (t < t0n + t1n) { half = 1; jl0 = (t - t0n) * 64; cnth = c1; }
  else return;  // out2 pre-zeroed (block-uniform exit, before any barrier)
  const int qrow0 = qt + wid * 16;
  const int qrb = (qt >> 4) + wid;
  const int ktb = half * 64 + (jl0 >> 4);
  const int sf0 = wid * 4;
  int korig[4]; bool vld[4];
#pragma unroll
  for (int nb = 0; nb < 4; nb++) {
    int j = jl0 + nb * 16 + l15;
    vld[nb] = j < cnth;
    korig[nb] = idxT[(b * 2 + half) * 1024 + j];
  }
  float psum[4][4] = {};  // [nb][r]
  for (int h = 0; h < HH; h++) {
    const int bh = b * HH + h;
    const int qoff = (bh * 128 + qrb) * 1024 + lane * 8;
    short8x fqr0 = *(const short8x*)(Qr + qoff);
    short8x fqr1 = *(const short8x*)(Qr + qoff + 512);
    short8x fqi0 = *(const short8x*)(Qi + qoff);
    short8x fqi1 = *(const short8x*)(Qi + qoff + 512);
    const float4 lv0 = *(const float4*)(Lp0 + (size_t)bh * SS + qrow0 + quad * 4);
    const float4 lv1 = *(const float4*)(Lp1 + (size_t)bh * SS + qrow0 + quad * 4);
    float li[4];
    li[0] = 1.0f / (lv0.x + lv1.x); li[1] = 1.0f / (lv0.y + lv1.y);
    li[2] = 1.0f / (lv0.z + lv1.z); li[3] = 1.0f / (lv0.w + lv1.w);
    // stage this head's 16 K frags (wave w: frags 4w..4w+3)
    const int rbb = bh * 128 + ktb;
    __syncthreads();   // protect prior-iteration Ks reads
#pragma unroll
    for (int fi = 0; fi < 4; fi++) {
      int f = sf0 + fi;
      int arr = f >> 3, rbl = (f >> 1) & 3, ks = f & 1;
      const unsigned short* src = (arr ? Ki : Kr) + ((size_t)(rbb + rbl) * 2 + ks) * 512 + lane * 8;
      gload16(src, &Ks[arr][rbl][ks][0]);
    }
    __syncthreads();   // staged data visible
#pragma unroll
    for (int nb = 0; nb < 4; nb++) {
      short8x bkr0 = *(const short8x*)&Ks[0][nb][0][lane * 8];
      short8x bkr1 = *(const short8x*)&Ks[0][nb][1][lane * 8];
      short8x bki0 = *(const short8x*)&Ks[1][nb][0][lane * 8];
      short8x bki1 = *(const short8x*)&Ks[1][nb][1][lane * 8];
      f32x4 sr = {0.f, 0.f, 0.f, 0.f};
      sr = mfma16(fqr0, bkr0, sr);  sr = mfma16(fqr1, bkr1, sr);
      sr = mfma16(fqi0, bki0, sr);  sr = mfma16(fqi1, bki1, sr);
      f32x4 sa = {0.f, 0.f, 0.f, 0.f};  // Qi.Kr
      sa = mfma16(fqi0, bkr0, sa);  sa = mfma16(fqi1, bkr1, sa);
      f32x4 sb = {0.f, 0.f, 0.f, 0.f};  // Qr.Ki
      sb = mfma16(fqr0, bki0, sb);  sb = mfma16(fqr1, bki1, sb);
#pragma unroll
      for (int r = 0; r < 4; r++) {
        float a = sr[r];
        float d = sa[r] - sb[r];
        float r2 = __builtin_fmaf(a, a, d * d);
        float inv = __builtin_amdgcn_rsqf(r2);
        float arg = inv * __builtin_fmaf(C1F, r2, C2F * a);
        float p = vld[nb] ? __builtin_amdgcn_exp2f(arg) * li[r] : 0.0f;  // select
        psum[nb][r] += p;
      }
    }
  }
#pragma unroll
  for (int nb = 0; nb < 4; nb++)
#pragma unroll
    for (int r = 0; r < 4; r++) {
      if (vld[nb]) {
        int qrow = qrow0 + quad * 4 + r;
        out2[((size_t)b * SS + qrow) * SS + korig[nb]] = psum[nb][r] * 0.0625f;
      }
    }
}

extern "C" void kernel_launch(void* const* d_in, const int* in_sizes, int n_in,
                              void* d_out, int out_size, void* d_ws, size_t ws_size,
                              hipStream_t stream) {
  const float* z_real = (const float*)d_in[0];
  const float* z_imag = (const float*)d_in[1];
  const float* Wq_r = (const float*)d_in[2];
  const float* Wq_i = (const float*)d_in[3];
  const float* Wk_r = (const float*)d_in[4];
  const float* Wk_i = (const float*)d_in[5];
  const float* Wv   = (const float*)d_in[6];
  const float* Wo_w = (const float*)d_in[7];
  const float* Wo_b = (const float*)d_in[8];
  const int*   mask = (const int*)d_in[9];
  char* ws = (char*)d_ws;

  // ws layout (bytes). ctxP0/ctxP1 ALIAS WcatT/Xcat: dead after gemm_proj (stream-serial).
  constexpr size_t QKV_BYTES = 8388608;  // B*H*S*DK*2
  unsigned short* Qr   = (unsigned short*)(ws + 0);
  unsigned short* Qi   = (unsigned short*)(ws + QKV_BYTES);
  unsigned short* Kr   = (unsigned short*)(ws + 2 * QKV_BYTES);
  unsigned short* Ki   = (unsigned short*)(ws + 3 * QKV_BYTES);
  unsigned short* VT   = (unsigned short*)(ws + 4 * QKV_BYTES);
  unsigned short* ctx  = (unsigned short*)(ws + 5 * QKV_BYTES);              // 8 MB bf16
  unsigned short* WcatT= (unsigned short*)(ws + 50331648);                   // 20 MB
  unsigned short* WoT  = (unsigned short*)(ws + 71303168);                   // 2 MB
  unsigned short* Xcat = (unsigned short*)(ws + 73400320);                   // 16 MB
  float* ctxP0 = (float*)(ws + 50331648);                                    // aliases WcatT (16 MB)
  float* ctxP1 = (float*)(ws + 73400320);                                    // aliases Xcat (16 MB)
  float* Lp0   = (float*)(ws + 90177536);                                    // 256 KB
  float* Lp1   = (float*)(ws + 90439680);                                    // 256 KB

  float* out  = (float*)d_out;
  float* out2 = out + (size_t)BB * SS * DD;

  // Compaction tables + schedule in d_out scratch (dead until gemm_out;
  // probsmean reads idxT before combine/gemm_out).
  unsigned short* posT = (unsigned short*)out;       // [2][2048] = 8 KB
  unsigned short* idxT = posT + 4096;                // [2][2][1024] = 8 KB
  int* cntT = (int*)(idxT + 4096);                   // [2][2] = 16 B
  int* nactT = cntT + 4;                             // 4 B
  ushort2* schedT = (ushort2*)(cntT + 8);            // 1280 x 4 B = 5 KB
  // Xc2 (compacted X rows for K/V projection, 16 MB) aliases out2 scratch:
  // dead after gemm_proj; out2 zeroing after gemm_proj.
  unsigned short* Xc2 = (unsigned short*)out2;

  mask_scan_kernel<<<dim3(4), dim3(256), 0, stream>>>(mask, posT, idxT, cntT);
  build_sched_kernel<<<dim3(1), dim3(256), 0, stream>>>(cntT, schedT, nactT);
  pack_w_kernel<<<dim3(2816), dim3(256), 0, stream>>>(Wq_r, Wq_i, Wk_r, Wk_i, Wv, Wo_w, WcatT, WoT);
  pack_x_kernel<<<dim3(4096), dim3(256), 0, stream>>>(z_real, z_imag, posT, Xcat, Xc2);
  gemm_proj_kernel<<<dim3(1280), dim3(256), 0, stream>>>(Xcat, Xc2, WcatT, cntT, schedT, nactT, Qr, Qi, Kr, Ki, VT);
  zero_kernel<<<dim3(8192), dim3(256), 0, stream>>>((float4*)out2);          // 32 MB: masked cols = 0
  flash_kernel<<<dim3(16, 16, 4), dim3(256), 0, stream>>>(Qr, Qi, Kr, Ki, VT, cntT, ctxP0, ctxP1, Lp0, Lp1);
  probsmean_kernel<<<dim3(32, 32, 2), dim3(256), 0, stream>>>(Qr, Qi, Kr, Ki, cntT, idxT, Lp0, Lp1, out2);
  combine_kernel<<<dim3(4096), dim3(256), 0, stream>>>(ctxP0, ctxP1, Lp0, Lp1, ctx);
  gemm_out_kernel<<<dim3(64, 8), dim3(256), 0, stream>>>(ctx, WoT, Wo_b, out);
}